// Round 4
// baseline (19.642 us; speedup 1.0000x reference)
//
#include <hip/hip_runtime.h>
#include <math.h>

#define KACC 10
#define CH1 12   // first chunk rows (covers ~99.9% of columns)
#define CH2 8    // continuation chunk rows

__global__ __launch_bounds__(256)
void sss_kernel(const float* __restrict__ Z, const float* __restrict__ U,
                const float* __restrict__ uu, const float* __restrict__ ga,
                const float* __restrict__ la, float* __restrict__ out,
                int P, int B, int nbScan, int perK, int vec4)
{
#pragma clang fp contract(off)
    const size_t KP = (size_t)KACC * (size_t)P;
    float* o_z        = out;
    float* o_zmean    = out + KP;
    float* o_theta    = out + KP + (size_t)P;
    float* o_alpha    = out + 2 * KP + (size_t)P;
    float* o_logalpha = out + 2 * KP + 2 * (size_t)P;

    const int bid = blockIdx.x;

    if (bid < nbScan) {
        // ---------------- SCAN ROLE: Marsaglia-Tsang first-K compaction ----------------
        const int p = bid * blockDim.x + threadIdx.x;
        if (p >= P) return;

        const float g = ga[p];
        const float alpha = fmaxf(g, 0.0f) + 1.0f;     // relu + 1
        const float d     = alpha - (1.0f / 3.0f);
        const float c     = 1.0f / sqrtf(9.0f * d);
        const float neg_inv_c = -(1.0f / c);

        float th[KACC];
#pragma unroll
        for (int k = 0; k < KACC; ++k) th[k] = 0.0f;
        int cnt = 0;

        // chunk 1: rows 0..CH1-1, all loads issued up front (MLP)
        {
            float zv[CH1], wv[CH1];
#pragma unroll
            for (int i = 0; i < CH1; ++i) {
                const size_t off = (size_t)i * (size_t)P + (size_t)p;
                zv[i] = Z[off];
                wv[i] = U[off];
            }
#pragma unroll
            for (int i = 0; i < CH1; ++i) {
                float z  = zv[i];
                float Uv = wv[i];
                float t  = 1.0f + c * z;
                float V  = (t * t) * t;                // (1+cZ)**3
                float rhs = ((0.5f * (z * z) + d) - d * V) + d * logf(V);
                bool acc = (z > neg_inv_c) && (logf(Uv) < rhs) && (cnt < KACC);
                float val = d * V;
#pragma unroll
                for (int k = 0; k < KACC; ++k)
                    th[k] = (acc && cnt == k) ? val : th[k];
                cnt += acc ? 1 : 0;
            }
        }

        // rare continuation (~0.1% of columns, ~6% of waves)
        if (cnt < KACC) {
            for (int base = CH1; base < B; base += CH2) {
                float zv[CH2], wv[CH2];
#pragma unroll
                for (int i = 0; i < CH2; ++i) {
                    const int r = base + i;
                    const size_t off = (size_t)r * (size_t)P + (size_t)p;
                    zv[i] = (r < B) ? Z[off] : __int_as_float(0x7fc00000); // NaN -> reject
                    wv[i] = (r < B) ? U[off] : 1.0f;
                }
#pragma unroll
                for (int i = 0; i < CH2; ++i) {
                    float z  = zv[i];
                    float Uv = wv[i];
                    float t  = 1.0f + c * z;
                    float V  = (t * t) * t;
                    float rhs = ((0.5f * (z * z) + d) - d * V) + d * logf(V);
                    bool acc = (z > neg_inv_c) && (logf(Uv) < rhs) && (cnt < KACC);
                    float val = d * V;
#pragma unroll
                    for (int k = 0; k < KACC; ++k)
                        th[k] = (acc && cnt == k) ? val : th[k];
                    cnt += acc ? 1 : 0;
                }
                if (cnt >= KACC) break;
            }
        }

#pragma unroll
        for (int k = 0; k < KACC; ++k)
            o_theta[(size_t)k * (size_t)P + (size_t)p] = th[k];
        o_alpha[p] = alpha;

    } else {
        // ---------------- GATE ROLE: one (k, p-chunk) slice per block ----------------
        const int gb  = bid - nbScan;
        const int k   = gb / perK;
        const int blk = gb - k * perK;
        const float SHIFT = 0.060606062f;              // BETA * (-GAMMA/ZETA)

        if (vec4) {
            const int P4 = P >> 2;
            const int i4 = blk * blockDim.x + threadIdx.x;
            if (i4 >= P4) return;

            const float4 u4  = reinterpret_cast<const float4*>(uu + (size_t)k * (size_t)P)[i4];
            const float4 la4 = reinterpret_cast<const float4*>(la)[i4];

            float4 z4;
            {
                const float* us = (const float*)&u4;
                const float* ls = (const float*)&la4;
                float* zs = (float*)&z4;
#pragma unroll
                for (int j = 0; j < 4; ++j) {
                    float x = ((__logf(us[j]) - __logf(1.0f - us[j])) + ls[j]) * 1.5f;
                    float s = 1.0f / (1.0f + __expf(-x));
                    float zz = 1.2f * s - 0.1f;
                    zs[j] = fminf(fmaxf(zz, 0.0f), 1.0f);
                }
            }
            reinterpret_cast<float4*>(o_z + (size_t)k * (size_t)P)[i4] = z4;

            if (k == 0) {
                const float* ls = (const float*)&la4;
                float4 zm4;
                float* zm = (float*)&zm4;
#pragma unroll
                for (int j = 0; j < 4; ++j)
                    zm[j] = 1.0f / (1.0f + __expf(-(ls[j] - SHIFT)));
                reinterpret_cast<float4*>(o_zmean)[i4]    = zm4;
                reinterpret_cast<float4*>(o_logalpha)[i4] = la4;
            }
        } else {
            const int p = blk * blockDim.x + threadIdx.x;
            if (p >= P) return;
            const float u = uu[(size_t)k * (size_t)P + (size_t)p];
            const float lalpha = la[p];
            float x = ((__logf(u) - __logf(1.0f - u)) + lalpha) * 1.5f;
            float s = 1.0f / (1.0f + __expf(-x));
            float zz = 1.2f * s - 0.1f;
            o_z[(size_t)k * (size_t)P + (size_t)p] = fminf(fmaxf(zz, 0.0f), 1.0f);
            if (k == 0) {
                o_zmean[p]    = 1.0f / (1.0f + __expf(-(lalpha - SHIFT)));
                o_logalpha[p] = lalpha;
            }
        }
    }
}

extern "C" void kernel_launch(void* const* d_in, const int* in_sizes, int n_in,
                              void* d_out, int out_size, void* d_ws, size_t ws_size,
                              hipStream_t stream) {
    const float* Z  = (const float*)d_in[0];
    const float* U  = (const float*)d_in[1];
    const float* uu = (const float*)d_in[2];
    const float* ga = (const float*)d_in[3];
    const float* la = (const float*)d_in[4];
    float* out = (float*)d_out;

    const int P = in_sizes[3];            // gamma_alpha is [P]
    const int B = in_sizes[0] / P;        // Z is [B,P]
    const int K = in_sizes[2] / P;        // u is [K,P]  (== KACC)

    const int block  = 256;
    const int nbScan = (P + block - 1) / block;
    const int vec4   = (P % 4 == 0) ? 1 : 0;
    const int perK   = vec4 ? ((P / 4 + block - 1) / block)
                            : ((P + block - 1) / block);
    const int grid   = nbScan + K * perK;
    sss_kernel<<<grid, block, 0, stream>>>(Z, U, uu, ga, la, out, P, B, nbScan, perK, vec4);
}

// Round 5
// 16.511 us; speedup vs baseline: 1.1896x; 1.1896x over previous
//
#include <hip/hip_runtime.h>
#include <math.h>

#define KACC 10
#define NRG 4      // parallel rowgroups per column
#define RPG 3      // rows per group -> 12 rows scanned up front
#define SCOLS 64   // columns per scan block

__global__ __launch_bounds__(256)
void sss_kernel(const float* __restrict__ Z, const float* __restrict__ U,
                const float* __restrict__ uu, const float* __restrict__ ga,
                const float* __restrict__ la, float* __restrict__ out,
                int P, int B, int nbScan, int perK, int vec4)
{
#pragma clang fp contract(off)
    const size_t KP = (size_t)KACC * (size_t)P;
    float* o_z        = out;
    float* o_zmean    = out + KP;
    float* o_theta    = out + KP + (size_t)P;
    float* o_alpha    = out + 2 * KP + (size_t)P;
    float* o_logalpha = out + 2 * KP + 2 * (size_t)P;

    const int bid = blockIdx.x;

    if (bid < nbScan) {
        // ---------------- SCAN ROLE: row-parallel Marsaglia-Tsang compaction ----------------
        __shared__ float s_val[NRG * RPG][SCOLS];
        __shared__ int   s_msk[NRG][SCOLS];

        const int t    = threadIdx.x;
        const int lane = t & (SCOLS - 1);
        const int rg   = t >> 6;
        const int col  = bid * SCOLS + lane;
        const bool cok = (col < P);

        const float g = cok ? ga[col] : 1.0f;
        const float alpha = fmaxf(g, 0.0f) + 1.0f;     // relu + 1
        const float d     = alpha - (1.0f / 3.0f);
        const float c     = 1.0f / sqrtf(9.0f * d);
        const float neg_inv_c = -(1.0f / c);

        // phase 1: rows rg*RPG .. rg*RPG+RPG-1, accept bit + candidate value
        {
            float zv[RPG], wv[RPG];
#pragma unroll
            for (int j = 0; j < RPG; ++j) {
                const int row = rg * RPG + j;
                const size_t off = (size_t)row * (size_t)P + (size_t)col;
                const bool ok = cok && (row < B);
                zv[j] = ok ? Z[off] : __int_as_float(0x7fc00000);  // NaN -> reject
                wv[j] = ok ? U[off] : 1.0f;
            }
            int m = 0;
#pragma unroll
            for (int j = 0; j < RPG; ++j) {
                float z  = zv[j];
                float Uv = wv[j];
                float tt = 1.0f + c * z;
                float V  = (tt * tt) * tt;             // (1+cZ)**3
                float rhs = ((0.5f * (z * z) + d) - d * V) + d * logf(V);
                bool acc = (z > neg_inv_c) && (logf(Uv) < rhs);
                m |= acc ? (1 << j) : 0;
                s_val[rg * RPG + j][lane] = d * V;
            }
            s_msk[rg][lane] = m;
        }
        __syncthreads();
        if (rg != 0) return;                           // waves 1-3 done

        // phase 2 (wave 0): order-preserving first-K merge of the 12 candidates
        const int mask = s_msk[0][lane]
                       | (s_msk[1][lane] << RPG)
                       | (s_msk[2][lane] << (2 * RPG))
                       | (s_msk[3][lane] << (3 * RPG));

        float th[KACC];
#pragma unroll
        for (int k = 0; k < KACC; ++k) th[k] = 0.0f;
        int cnt = 0;
#pragma unroll
        for (int j = 0; j < NRG * RPG; ++j) {
            bool acc = ((mask >> j) & 1) && (cnt < KACC);
            float val = s_val[j][lane];
#pragma unroll
            for (int k = 0; k < KACC; ++k)
                th[k] = (acc && cnt == k) ? val : th[k];
            cnt += acc ? 1 : 0;
        }

        // rare continuation (~0.1% of columns): chunked per-lane scan of rows 12..B-1
        if (cnt < KACC) {
            for (int base = NRG * RPG; base < B; base += 4) {
                float zv[4], wv[4];
#pragma unroll
                for (int i = 0; i < 4; ++i) {
                    const int row = base + i;
                    const size_t off = (size_t)row * (size_t)P + (size_t)col;
                    const bool ok = cok && (row < B);
                    zv[i] = ok ? Z[off] : __int_as_float(0x7fc00000);
                    wv[i] = ok ? U[off] : 1.0f;
                }
#pragma unroll
                for (int i = 0; i < 4; ++i) {
                    float z  = zv[i];
                    float Uv = wv[i];
                    float tt = 1.0f + c * z;
                    float V  = (tt * tt) * tt;
                    float rhs = ((0.5f * (z * z) + d) - d * V) + d * logf(V);
                    bool acc = (z > neg_inv_c) && (logf(Uv) < rhs) && (cnt < KACC);
                    float val = d * V;
#pragma unroll
                    for (int k = 0; k < KACC; ++k)
                        th[k] = (acc && cnt == k) ? val : th[k];
                    cnt += acc ? 1 : 0;
                }
                if (cnt >= KACC) break;
            }
        }

        if (cok) {
#pragma unroll
            for (int k = 0; k < KACC; ++k)
                o_theta[(size_t)k * (size_t)P + (size_t)col] = th[k];
            o_alpha[col] = alpha;
        }

    } else {
        // ---------------- GATE ROLE: one (k, p-chunk) slice per block ----------------
        const int gb  = bid - nbScan;
        const int k   = gb / perK;
        const int blk = gb - k * perK;
        const float SHIFT = 0.060606062f;              // BETA * (-GAMMA/ZETA)

        if (vec4) {
            const int P4 = P >> 2;
            const int i4 = blk * blockDim.x + threadIdx.x;
            if (i4 >= P4) return;

            const float4 u4  = reinterpret_cast<const float4*>(uu + (size_t)k * (size_t)P)[i4];
            const float4 la4 = reinterpret_cast<const float4*>(la)[i4];

            float4 z4;
            {
                const float* us = (const float*)&u4;
                const float* ls = (const float*)&la4;
                float* zs = (float*)&z4;
#pragma unroll
                for (int j = 0; j < 4; ++j) {
                    float x = ((__logf(us[j]) - __logf(1.0f - us[j])) + ls[j]) * 1.5f;
                    float s = 1.0f / (1.0f + __expf(-x));
                    float zz = 1.2f * s - 0.1f;
                    zs[j] = fminf(fmaxf(zz, 0.0f), 1.0f);
                }
            }
            reinterpret_cast<float4*>(o_z + (size_t)k * (size_t)P)[i4] = z4;

            if (k == 0) {
                const float* ls = (const float*)&la4;
                float4 zm4;
                float* zm = (float*)&zm4;
#pragma unroll
                for (int j = 0; j < 4; ++j)
                    zm[j] = 1.0f / (1.0f + __expf(-(ls[j] - SHIFT)));
                reinterpret_cast<float4*>(o_zmean)[i4]    = zm4;
                reinterpret_cast<float4*>(o_logalpha)[i4] = la4;
            }
        } else {
            const int p = blk * blockDim.x + threadIdx.x;
            if (p >= P) return;
            const float u = uu[(size_t)k * (size_t)P + (size_t)p];
            const float lalpha = la[p];
            float x = ((__logf(u) - __logf(1.0f - u)) + lalpha) * 1.5f;
            float s = 1.0f / (1.0f + __expf(-x));
            float zz = 1.2f * s - 0.1f;
            o_z[(size_t)k * (size_t)P + (size_t)p] = fminf(fmaxf(zz, 0.0f), 1.0f);
            if (k == 0) {
                o_zmean[p]    = 1.0f / (1.0f + __expf(-(lalpha - SHIFT)));
                o_logalpha[p] = lalpha;
            }
        }
    }
}

extern "C" void kernel_launch(void* const* d_in, const int* in_sizes, int n_in,
                              void* d_out, int out_size, void* d_ws, size_t ws_size,
                              hipStream_t stream) {
    const float* Z  = (const float*)d_in[0];
    const float* U  = (const float*)d_in[1];
    const float* uu = (const float*)d_in[2];
    const float* ga = (const float*)d_in[3];
    const float* la = (const float*)d_in[4];
    float* out = (float*)d_out;

    const int P = in_sizes[3];            // gamma_alpha is [P]
    const int B = in_sizes[0] / P;        // Z is [B,P]
    const int K = in_sizes[2] / P;        // u is [K,P]  (== KACC)

    const int block  = 256;
    const int nbScan = (P + SCOLS - 1) / SCOLS;        // 64 columns per scan block
    const int vec4   = (P % 4 == 0) ? 1 : 0;
    const int perK   = vec4 ? ((P / 4 + block - 1) / block)
                            : ((P + block - 1) / block);
    const int grid   = nbScan + K * perK;
    sss_kernel<<<grid, block, 0, stream>>>(Z, U, uu, ga, la, out, P, B, nbScan, perK, vec4);
}